// Round 12
// baseline (188.281 us; speedup 1.0000x reference)
//
#include <hip/hip_runtime.h>
#include <hip/hip_bf16.h>
#include <math.h>

typedef float f32x4 __attribute__((ext_vector_type(4)));
typedef short bf16x8_t __attribute__((ext_vector_type(8)));
typedef unsigned short u16;
typedef unsigned int u32;
typedef u32 u32x2 __attribute__((ext_vector_type(2)));

#define SEQ     2048
#define DMODEL  1024
#define HEADS   16
#define DK      64

__device__ __forceinline__ u16 f2bf(float f) {
    union { float f; unsigned int u; } x; x.f = f;
    unsigned int r = x.u + 0x7fffu + ((x.u >> 16) & 1u);
    return (u16)(r >> 16);
}

__device__ __forceinline__ float bf2f(u16 v) {
    union { u32 u; float f; } x; x.u = ((u32)v) << 16; return x.f;
}

// pack two f32 -> 2x bf16 (RNE), S0 -> low half
__device__ __forceinline__ u32 cvt_pk_bf16(float lo, float hi) {
    u32 r;
    asm("v_cvt_pk_bf16_f32 %0, %1, %2" : "=v"(r) : "v"(lo), "v"(hi));
    return r;
}

// XOR swizzle for 128B-row-stride LDS tiles: byte ^= ((row ^ row>>3) & 7) << 4
__device__ __forceinline__ int swz(int row) { return ((row ^ (row >> 3)) & 7) << 4; }

__device__ __forceinline__ void gload_lds16(const u16* g, u16* l) {
    __builtin_amdgcn_global_load_lds((const __attribute__((address_space(1))) void*)g,
                                     (__attribute__((address_space(3))) void*)l,
                                     16, 0, 0);
}

// ---------------------------------------------------------------------------
// fused fp32 -> bf16 conversion for x + 4 weights
// ---------------------------------------------------------------------------
__global__ void cvt5(const float* __restrict__ s0, const float* __restrict__ s1,
                     const float* __restrict__ s2, const float* __restrict__ s3,
                     const float* __restrict__ s4,
                     u16* __restrict__ d0, u16* __restrict__ d1, u16* __restrict__ d2,
                     u16* __restrict__ d3, u16* __restrict__ d4,
                     int n0, int n1, int n2, int n3, int n4)
{
    const float* s; u16* d; int n;
    switch (blockIdx.y) {
        case 0: s = s0; d = d0; n = n0; break;
        case 1: s = s1; d = d1; n = n1; break;
        case 2: s = s2; d = d2; n = n2; break;
        case 3: s = s3; d = d3; n = n3; break;
        default: s = s4; d = d4; n = n4; break;
    }
    int i = (blockIdx.x * 256 + threadIdx.x) * 4;
    if (i >= n) return;
    float4 v = *(const float4*)(s + i);
    ushort4 o;
    o.x = f2bf(v.x); o.y = f2bf(v.y); o.z = f2bf(v.z); o.w = f2bf(v.w);
    *(ushort4*)(d + i) = o;
}

// ---------------------------------------------------------------------------
// GEMM: C[m][n] = sum_k A[m][k] * B[n][k]  (row-major, K contiguous, BK=64)
// BM=128, BN template (128: 4 waves of 64x64; 64: 4 waves of 32x64).
// blockIdx.z selects one of up to 3 (B, C) pairs (fused QKV).
// NOTE on block mapping (R11 lesson): the natural dispatch order already
// gives XCD locality — L%8 = blockIdx.x%8 = row%8, so each XCD owns 4 fixed
// A-row panels (1MB, L2-resident across all column/z panels) and streams B.
// An explicit column-grouped remap (R11) inverted this and REGRESSED ~8.5us.
// Keep the direct mapping.
// ---------------------------------------------------------------------------
template<int OUTBF16, int BN>
__launch_bounds__(256, 2)
__global__ void gemm_bt(const u16* __restrict__ A,
                        const u16* __restrict__ B0, const u16* __restrict__ B1,
                        const u16* __restrict__ B2,
                        void* C0v, void* C1v, void* C2v,
                        int M, int N, int K)
{
    const u16* B = (blockIdx.z == 0) ? B0 : (blockIdx.z == 1 ? B1 : B2);
    void* Cv     = (blockIdx.z == 0) ? C0v : (blockIdx.z == 1 ? C1v : C2v);

    __shared__ u16 Als[128 * 64];
    __shared__ u16 Bls[BN * 64];

    const int tid = threadIdx.x;
    const int w = tid >> 6, l = tid & 63;
    const int rl = l & 15, rh = l >> 4;
    const int row0 = blockIdx.x * 128, col0 = blockIdx.y * BN;
    constexpr int MI = (BN == 128) ? 4 : 2;
    const int wr = (BN == 128) ? (w >> 1) * 64 : w * 32;
    const int wc = (BN == 128) ? (w & 1) * 64 : 0;

    f32x4 acc[MI][4];
    #pragma unroll
    for (int i = 0; i < MI; i++)
        #pragma unroll
        for (int j = 0; j < 4; j++)
            acc[i][j] = (f32x4){0.f, 0.f, 0.f, 0.f};

    for (int kt = 0; kt < K; kt += 64) {
        #pragma unroll
        for (int i = 0; i < 4; i++) {
            int c = i * 256 + tid;
            int r = c >> 3, s = c & 7;
            gload_lds16(A + (size_t)(row0 + r) * K + kt + s * 8, &Als[(i * 256 + w * 64) * 8]);
        }
        #pragma unroll
        for (int i = 0; i < BN / 32; i++) {
            int c = i * 256 + tid;
            int r = c >> 3, s = c & 7;
            gload_lds16(B + (size_t)(col0 + r) * K + kt + s * 8, &Bls[(i * 256 + w * 64) * 8]);
        }
        __syncthreads();

        bf16x8_t af[MI][2], bfr[4][2];
        #pragma unroll
        for (int mi = 0; mi < MI; mi++)
            #pragma unroll
            for (int k0 = 0; k0 < 2; k0++)
                af[mi][k0] = *(const bf16x8_t*)&Als[(wr + mi * 16 + rl) * 64 + k0 * 32 + rh * 8];
        #pragma unroll
        for (int ni = 0; ni < 4; ni++)
            #pragma unroll
            for (int k0 = 0; k0 < 2; k0++)
                bfr[ni][k0] = *(const bf16x8_t*)&Bls[(wc + ni * 16 + rl) * 64 + k0 * 32 + rh * 8];

        #pragma unroll
        for (int mi = 0; mi < MI; mi++)
            #pragma unroll
            for (int ni = 0; ni < 4; ni++)
                #pragma unroll
                for (int k0 = 0; k0 < 2; k0++)
                    acc[mi][ni] = __builtin_amdgcn_mfma_f32_16x16x32_bf16(
                        af[mi][k0], bfr[ni][k0], acc[mi][ni], 0, 0, 0);
        __syncthreads();
    }

    #pragma unroll
    for (int mi = 0; mi < MI; mi++)
        #pragma unroll
        for (int ni = 0; ni < 4; ni++) {
            int r = row0 + wr + mi * 16 + rh * 4;
            int c = col0 + wc + ni * 16 + rl;
            #pragma unroll
            for (int j = 0; j < 4; j++) {
                if (OUTBF16) ((u16*)Cv)[(size_t)(r + j) * N + c] = f2bf(acc[mi][ni][j]);
                else         ((float*)Cv)[(size_t)(r + j) * N + c] = acc[mi][ni][j];
            }
        }
}

// ---------------------------------------------------------------------------
// Causal flash attention. grid = (32 bh, 32 q-tiles big-first) = 1024 blocks
// = 4 blocks/CU. bh = blockIdx.x: all 32 blocks of a head share L%8 -> one
// XCD -> KV re-reads L2-local (verified R8: FETCH 133->22MB). Swapped QK^T
// (T12), K dbuf via global_load_lds, V dbuf async-stage split, one barrier
// per tile, T13 defer-max, P-pack via v_cvt_pk_bf16_f32 (R11: -9us).
// ---------------------------------------------------------------------------
__launch_bounds__(256, 4)
__global__ void attn_fwd(const u16* __restrict__ Q, const u16* __restrict__ Kp,
                         const u16* __restrict__ Vp, u16* __restrict__ O)
{
    const int bh  = blockIdx.x;              // 0..31; XCD = bx%8 fixed per head
    const int qti = 31 - blockIdx.y;         // big-first
    const int b = bh >> 4, h = bh & 15;
    const int tid = threadIdx.x, w = tid >> 6, l = tid & 63;
    const int rl = l & 15, rh = l >> 4;

    __shared__ u16 Kls[2][64 * 64];          // K dbuf: [kv][d], swizzled
    __shared__ u16 Vt[2][64 * 64];           // V^T dbuf: [d][kv], swizzled
    __shared__ u16 Pls[4][16 * 64];          // per-wave P tile [q][kv]

    const size_t base = (size_t)b * SEQ * DMODEL + h * DK;
    const float SC = 0.125f * 1.44269504f;   // 1/sqrt(dk) * log2(e)
    const int krl8 = l >> 3, ks = l & 7;     // K staging: row-in-8, 16B seg
    const int rpair = tid >> 3, dseg = tid & 7;   // V staging assignment

    const int nt = qti + 1;                  // kv tiles 0..qti
    const int qt0 = qti * 64;

    // Q fragments (16 rows per wave), pre-scaled by SC
    bf16x8_t qf[2];
    #pragma unroll
    for (int k0 = 0; k0 < 2; k0++) {
        int row = qt0 + w * 16 + rl;
        bf16x8_t qr = *(const bf16x8_t*)(Q + base + (size_t)row * DMODEL + k0 * 32 + rh * 8);
        #pragma unroll
        for (int j = 0; j < 8; j++)
            qf[k0][j] = (short)f2bf(bf2f((u16)qr[j]) * SC);
    }

    f32x4 oacc[4];
    float mrun = -INFINITY, lrun = 0.f;      // per-lane: q-row = rl
    #pragma unroll
    for (int nd = 0; nd < 4; nd++) oacc[nd] = (f32x4){0.f, 0.f, 0.f, 0.f};

    // --- prologue: stage K(0) -> Kls[0], V(0) -> Vt[0] ---
    #pragma unroll
    for (int c = 0; c < 2; c++) {
        int kr = w * 16 + c * 8 + krl8;
        int sseg = ks ^ ((kr ^ (kr >> 3)) & 7);
        gload_lds16(Kp + base + (size_t)kr * DMODEL + sseg * 8,
                    &Kls[0][(w * 16 + c * 8) * 64]);
    }
    {
        const u16* vg = Vp + base + (size_t)(2 * rpair) * DMODEL + dseg * 8;
        bf16x8_t v0 = *(const bf16x8_t*)vg;
        bf16x8_t v1 = *(const bf16x8_t*)(vg + DMODEL);
        #pragma unroll
        for (int j = 0; j < 8; j++) {
            int d = dseg * 8 + j;
            u32 pk = (u32)(u16)v0[j] | ((u32)(u16)v1[j] << 16);
            *(u32*)((char*)&Vt[0][0] + ((d * 128 + rpair * 4) ^ swz(d))) = pk;
        }
    }
    __syncthreads();

    for (int t = 0; t < nt; t++) {
        const int cur = t & 1;
        const bool more = (t + 1 < nt);
        bf16x8_t vv0, vv1;

        // issue K(t+1) -> Kls[cur^1] (arrives at end-of-tile barrier)
        // and V(t+1) reg loads (written to LDS after PV)
        if (more) {
            #pragma unroll
            for (int c = 0; c < 2; c++) {
                int kr = w * 16 + c * 8 + krl8;
                int sseg = ks ^ ((kr ^ (kr >> 3)) & 7);
                gload_lds16(Kp + base + (size_t)((t + 1) * 64 + kr) * DMODEL + sseg * 8,
                            &Kls[cur ^ 1][(w * 16 + c * 8) * 64]);
            }
            const u16* vg = Vp + base + (size_t)((t + 1) * 64 + 2 * rpair) * DMODEL + dseg * 8;
            vv0 = *(const bf16x8_t*)vg;
            vv1 = *(const bf16x8_t*)(vg + DMODEL);
        }

        // --- S^T = K Q^T : sa[ni][j] holds q = rl, kv = ni*16+rh*4+j ---
        f32x4 sa[4];
        #pragma unroll
        for (int ni = 0; ni < 4; ni++) sa[ni] = (f32x4){0.f, 0.f, 0.f, 0.f};
        #pragma unroll
        for (int k0 = 0; k0 < 2; k0++) {
            bf16x8_t kf[4];
            #pragma unroll
            for (int ni = 0; ni < 4; ni++) {
                int row = ni * 16 + rl;
                kf[ni] = *(const bf16x8_t*)((const char*)&Kls[cur][0] +
                          (((row * 64 + k0 * 32 + rh * 8) * 2) ^ swz(row)));
            }
            #pragma unroll
            for (int ni = 0; ni < 4; ni++)
                sa[ni] = __builtin_amdgcn_mfma_f32_16x16x32_bf16(
                    kf[ni], qf[k0], sa[ni], 0, 0, 0);
        }

        // --- causal mask (diag tile only): kv_local > q_local ---
        if (t + 1 == nt) {
            const int ql = w * 16 + rl;
            #pragma unroll
            for (int ni = 0; ni < 4; ni++)
                #pragma unroll
                for (int j = 0; j < 4; j++)
                    if (ni * 16 + rh * 4 + j > ql) sa[ni][j] = -INFINITY;
        }

        // --- in-lane row max (tree) + 2-step cross-rh reduce ---
        float m0, m1, m2, m3, mx;
        m0 = fmaxf(fmaxf(sa[0][0], sa[0][1]), fmaxf(sa[0][2], sa[0][3]));
        m1 = fmaxf(fmaxf(sa[1][0], sa[1][1]), fmaxf(sa[1][2], sa[1][3]));
        m2 = fmaxf(fmaxf(sa[2][0], sa[2][1]), fmaxf(sa[2][2], sa[2][3]));
        m3 = fmaxf(fmaxf(sa[3][0], sa[3][1]), fmaxf(sa[3][2], sa[3][3]));
        mx = fmaxf(fmaxf(m0, m1), fmaxf(m2, m3));
        mx = fmaxf(mx, __shfl_xor(mx, 16, 64));
        mx = fmaxf(mx, __shfl_xor(mx, 32, 64));

        // --- T13 defer-max: rescale only when max grew > 8 (log2) ---
        if (__any(mx - mrun > 8.f)) {
            const float mn = fmaxf(mrun, mx);
            const float alpha = exp2f(mrun - mn);   // for q-row rl
            mrun = mn;
            lrun *= alpha;
            #pragma unroll
            for (int j = 0; j < 4; j++) {
                // oacc rows are q = rh*4+j -> fetch that row's alpha
                float aj = __shfl(alpha, (l & 48) | (rh * 4 + j), 64);
                #pragma unroll
                for (int nd = 0; nd < 4; nd++) oacc[nd][j] *= aj;
            }
        }

        // --- exp + in-lane sum + 2-step cross-rh reduce ---
        float s0 = 0.f, s1 = 0.f;
        #pragma unroll
        for (int ni = 0; ni < 4; ni++) {
            #pragma unroll
            for (int j = 0; j < 4; j++) {
                float p = exp2f(sa[ni][j] - mrun);
                sa[ni][j] = p;
                if (ni < 2) s0 += p; else s1 += p;
            }
        }
        float ss = s0 + s1;
        ss += __shfl_xor(ss, 16, 64);
        ss += __shfl_xor(ss, 32, 64);
        lrun += ss;

        // P (bf16) -> per-wave LDS [q=rl][kv], cvt_pk + packed b64 writes
        #pragma unroll
        for (int ni = 0; ni < 4; ni++) {
            u32x2 pk;
            pk.x = cvt_pk_bf16(sa[ni][0], sa[ni][1]);
            pk.y = cvt_pk_bf16(sa[ni][2], sa[ni][3]);
            *(u32x2*)((char*)&Pls[w][0] +
                      (((rl * 64 + ni * 16 + rh * 4) * 2) ^ swz(rl))) = pk;
        }

        // --- O += P V ---
        #pragma unroll
        for (int k0 = 0; k0 < 2; k0++) {
            bf16x8_t pf = *(const bf16x8_t*)((const char*)&Pls[w][0] +
                           (((rl * 64 + k0 * 32 + rh * 8) * 2) ^ swz(rl)));
            bf16x8_t vf[4];
            #pragma unroll
            for (int nd = 0; nd < 4; nd++) {
                int row = nd * 16 + rl;
                vf[nd] = *(const bf16x8_t*)((const char*)&Vt[cur][0] +
                          (((row * 64 + k0 * 32 + rh * 8) * 2) ^ swz(row)));
            }
            #pragma unroll
            for (int nd = 0; nd < 4; nd++)
                oacc[nd] = __builtin_amdgcn_mfma_f32_16x16x32_bf16(
                    pf, vf[nd], oacc[nd], 0, 0, 0);
        }

        // stage V(t+1) into the other buffer (its last reader was tile t-1,
        // protected by the previous barrier)
        if (more) {
            #pragma unroll
            for (int j = 0; j < 8; j++) {
                int d = dseg * 8 + j;
                u32 pk = (u32)(u16)vv0[j] | ((u32)(u16)vv1[j] << 16);
                *(u32*)((char*)&Vt[cur ^ 1][0] + ((d * 128 + rpair * 4) ^ swz(d))) = pk;
            }
        }
        __syncthreads();
    }

    // epilogue: O / l -> global (bf16); l for row q=rh*4+j via shfl
    float lq[4];
    #pragma unroll
    for (int j = 0; j < 4; j++)
        lq[j] = __shfl(lrun, (l & 48) | (rh * 4 + j), 64);
    #pragma unroll
    for (int nd = 0; nd < 4; nd++)
        #pragma unroll
        for (int j = 0; j < 4; j++) {
            int row = qt0 + w * 16 + rh * 4 + j;
            O[base + (size_t)row * DMODEL + nd * 16 + rl] =
                f2bf(oacc[nd][j] / lq[j]);
        }
}

// ---------------------------------------------------------------------------
extern "C" void kernel_launch(void* const* d_in, const int* in_sizes, int n_in,
                              void* d_out, int out_size, void* d_ws, size_t ws_size,
                              hipStream_t stream)
{
    const float* x  = (const float*)d_in[0];
    const float* wq = (const float*)d_in[1];
    const float* wk = (const float*)d_in[2];
    const float* wv = (const float*)d_in[3];
    const float* wo = (const float*)d_in[4];
    float* out = (float*)d_out;

    const size_t NX = (size_t)4096 * 1024;   // B*S*D
    const size_t NW = (size_t)1024 * 1024;

    u16* xb  = (u16*)d_ws;
    u16* wqb = xb  + NX;
    u16* wkb = wqb + NW;
    u16* wvb = wkb + NW;
    u16* wob = wvb + NW;
    u16* q   = wob + NW;
    u16* k   = q   + NX;
    u16* v   = k   + NX;
    u16* at  = v   + NX;

    cvt5<<<dim3(4096, 5), 256, 0, stream>>>(x, wq, wk, wv, wo,
                                            xb, wqb, wkb, wvb, wob,
                                            (int)NX, (int)NW, (int)NW, (int)NW, (int)NW);

    // Q/K/V projections: (4096x1024) @ (1024x1024)^T, fused over grid.z
    // (direct block mapping — implicit A-row XCD locality, see gemm_bt note)
    gemm_bt<1, 128><<<dim3(32, 8, 3), 256, 0, stream>>>(xb, wqb, wkb, wvb,
                                                        q, k, v, 4096, 1024, 1024);

    attn_fwd<<<dim3(32, 32), 256, 0, stream>>>(q, k, v, at);

    // output projection -> fp32 (BN=64 tile)
    gemm_bt<0, 64><<<dim3(32, 16, 1), 256, 0, stream>>>(at, wob, wob, wob,
                                                        out, out, out, 4096, 1024, 1024);
}

// Round 14
// 186.646 us; speedup vs baseline: 1.0088x; 1.0088x over previous
//
#include <hip/hip_runtime.h>
#include <hip/hip_bf16.h>
#include <math.h>

typedef float f32x4 __attribute__((ext_vector_type(4)));
typedef short bf16x8_t __attribute__((ext_vector_type(8)));
typedef unsigned short u16;
typedef unsigned int u32;
typedef u32 u32x2 __attribute__((ext_vector_type(2)));

#define SEQ     2048
#define DMODEL  1024
#define HEADS   16
#define DK      64

__device__ __forceinline__ u16 f2bf(float f) {
    union { float f; unsigned int u; } x; x.f = f;
    unsigned int r = x.u + 0x7fffu + ((x.u >> 16) & 1u);
    return (u16)(r >> 16);
}

__device__ __forceinline__ float bf2f(u16 v) {
    union { u32 u; float f; } x; x.u = ((u32)v) << 16; return x.f;
}

// pack two f32 -> 2x bf16 (RNE), S0 -> low half
__device__ __forceinline__ u32 cvt_pk_bf16(float lo, float hi) {
    u32 r;
    asm("v_cvt_pk_bf16_f32 %0, %1, %2" : "=v"(r) : "v"(lo), "v"(hi));
    return r;
}

// XOR swizzle for 128B-row-stride LDS tiles: byte ^= ((row ^ row>>3) & 7) << 4
__device__ __forceinline__ int swz(int row) { return ((row ^ (row >> 3)) & 7) << 4; }

__device__ __forceinline__ void gload_lds16(const u16* g, u16* l) {
    __builtin_amdgcn_global_load_lds((const __attribute__((address_space(1))) void*)g,
                                     (__attribute__((address_space(3))) void*)l,
                                     16, 0, 0);
}

// ---------------------------------------------------------------------------
// fused fp32 -> bf16 conversion, 8 elems/thread (2x float4 -> one 16B store)
// ---------------------------------------------------------------------------
__global__ void cvt5(const float* __restrict__ s0, const float* __restrict__ s1,
                     const float* __restrict__ s2, const float* __restrict__ s3,
                     const float* __restrict__ s4,
                     u16* __restrict__ d0, u16* __restrict__ d1, u16* __restrict__ d2,
                     u16* __restrict__ d3, u16* __restrict__ d4,
                     int n0, int n1, int n2, int n3, int n4)
{
    const float* s; u16* d; int n;
    switch (blockIdx.y) {
        case 0: s = s0; d = d0; n = n0; break;
        case 1: s = s1; d = d1; n = n1; break;
        case 2: s = s2; d = d2; n = n2; break;
        case 3: s = s3; d = d3; n = n3; break;
        default: s = s4; d = d4; n = n4; break;
    }
    int i = (blockIdx.x * 256 + threadIdx.x) * 8;
    if (i >= n) return;
    float4 a = *(const float4*)(s + i);
    float4 b = *(const float4*)(s + i + 4);
    bf16x8_t o;
    o[0] = (short)f2bf(a.x); o[1] = (short)f2bf(a.y);
    o[2] = (short)f2bf(a.z); o[3] = (short)f2bf(a.w);
    o[4] = (short)f2bf(b.x); o[5] = (short)f2bf(b.y);
    o[6] = (short)f2bf(b.z); o[7] = (short)f2bf(b.w);
    *(bf16x8_t*)(d + i) = o;
}

// ---------------------------------------------------------------------------
// GEMM: C[m][n] = sum_k A[m][k] * B[n][k]  (row-major, K contiguous, BK=64)
// BM=128, BN template (128: 4 waves of 64x64; 64: 4 waves of 32x64).
// blockIdx.z selects one of up to 3 (B, C) pairs (fused QKV).
// Direct block mapping (R11 lesson: natural dispatch already gives each XCD
// 4 fixed A-row panels; explicit remaps measured neutral-to-negative).
// __launch_bounds__(256,3): force VGPR<=168 -> 3 blocks/CU co-resident
// (m97's measured occupancy; the wave-overlap mechanism needs 3).
// ---------------------------------------------------------------------------
template<int OUTBF16, int BN>
__launch_bounds__(256, 3)
__global__ void gemm_bt(const u16* __restrict__ A,
                        const u16* __restrict__ B0, const u16* __restrict__ B1,
                        const u16* __restrict__ B2,
                        void* C0v, void* C1v, void* C2v,
                        int M, int N, int K)
{
    const u16* B = (blockIdx.z == 0) ? B0 : (blockIdx.z == 1 ? B1 : B2);
    void* Cv     = (blockIdx.z == 0) ? C0v : (blockIdx.z == 1 ? C1v : C2v);

    __shared__ u16 Als[128 * 64];
    __shared__ u16 Bls[BN * 64];

    const int tid = threadIdx.x;
    const int w = tid >> 6, l = tid & 63;
    const int rl = l & 15, rh = l >> 4;
    const int row0 = blockIdx.x * 128, col0 = blockIdx.y * BN;
    constexpr int MI = (BN == 128) ? 4 : 2;
    const int wr = (BN == 128) ? (w >> 1) * 64 : w * 32;
    const int wc = (BN == 128) ? (w & 1) * 64 : 0;

    f32x4 acc[MI][4];
    #pragma unroll
    for (int i = 0; i < MI; i++)
        #pragma unroll
        for (int j = 0; j < 4; j++)
            acc[i][j] = (f32x4){0.f, 0.f, 0.f, 0.f};

    for (int kt = 0; kt < K; kt += 64) {
        #pragma unroll
        for (int i = 0; i < 4; i++) {
            int c = i * 256 + tid;
            int r = c >> 3, s = c & 7;
            gload_lds16(A + (size_t)(row0 + r) * K + kt + s * 8, &Als[(i * 256 + w * 64) * 8]);
        }
        #pragma unroll
        for (int i = 0; i < BN / 32; i++) {
            int c = i * 256 + tid;
            int r = c >> 3, s = c & 7;
            gload_lds16(B + (size_t)(col0 + r) * K + kt + s * 8, &Bls[(i * 256 + w * 64) * 8]);
        }
        __syncthreads();

        bf16x8_t af[MI][2], bfr[4][2];
        #pragma unroll
        for (int mi = 0; mi < MI; mi++)
            #pragma unroll
            for (int k0 = 0; k0 < 2; k0++)
                af[mi][k0] = *(const bf16x8_t*)&Als[(wr + mi * 16 + rl) * 64 + k0 * 32 + rh * 8];
        #pragma unroll
        for (int ni = 0; ni < 4; ni++)
            #pragma unroll
            for (int k0 = 0; k0 < 2; k0++)
                bfr[ni][k0] = *(const bf16x8_t*)&Bls[(wc + ni * 16 + rl) * 64 + k0 * 32 + rh * 8];

        #pragma unroll
        for (int mi = 0; mi < MI; mi++)
            #pragma unroll
            for (int ni = 0; ni < 4; ni++)
                #pragma unroll
                for (int k0 = 0; k0 < 2; k0++)
                    acc[mi][ni] = __builtin_amdgcn_mfma_f32_16x16x32_bf16(
                        af[mi][k0], bfr[ni][k0], acc[mi][ni], 0, 0, 0);
        __syncthreads();
    }

    #pragma unroll
    for (int mi = 0; mi < MI; mi++)
        #pragma unroll
        for (int ni = 0; ni < 4; ni++) {
            int r = row0 + wr + mi * 16 + rh * 4;
            int c = col0 + wc + ni * 16 + rl;
            #pragma unroll
            for (int j = 0; j < 4; j++) {
                if (OUTBF16) ((u16*)Cv)[(size_t)(r + j) * N + c] = f2bf(acc[mi][ni][j]);
                else         ((float*)Cv)[(size_t)(r + j) * N + c] = acc[mi][ni][j];
            }
        }
}

// ---------------------------------------------------------------------------
// Causal flash attention. grid = (32 bh, 32 q-tiles big-first) = 1024 blocks
// = 4 blocks/CU. bh = blockIdx.x: all 32 blocks of a head share L%8 -> one
// XCD -> KV re-reads L2-local (verified R8: FETCH 133->22MB). Swapped QK^T
// (T12), K dbuf via global_load_lds, V dbuf async-stage split, one barrier
// per tile, T13 defer-max, cvt_pk P-pack (R11: -9us), T5 setprio around
// MFMA clusters (m191: +4-7% attn).
// ---------------------------------------------------------------------------
__launch_bounds__(256, 4)
__global__ void attn_fwd(const u16* __restrict__ Q, const u16* __restrict__ Kp,
                         const u16* __restrict__ Vp, u16* __restrict__ O)
{
    const int bh  = blockIdx.x;              // 0..31; XCD = bx%8 fixed per head
    const int qti = 31 - blockIdx.y;         // big-first
    const int b = bh >> 4, h = bh & 15;
    const int tid = threadIdx.x, w = tid >> 6, l = tid & 63;
    const int rl = l & 15, rh = l >> 4;

    __shared__ u16 Kls[2][64 * 64];          // K dbuf: [kv][d], swizzled
    __shared__ u16 Vt[2][64 * 64];           // V^T dbuf: [d][kv], swizzled
    __shared__ u16 Pls[4][16 * 64];          // per-wave P tile [q][kv]

    const size_t base = (size_t)b * SEQ * DMODEL + h * DK;
    const float SC = 0.125f * 1.44269504f;   // 1/sqrt(dk) * log2(e)
    const int krl8 = l >> 3, ks = l & 7;     // K staging: row-in-8, 16B seg
    const int rpair = tid >> 3, dseg = tid & 7;   // V staging assignment

    const int nt = qti + 1;                  // kv tiles 0..qti
    const int qt0 = qti * 64;

    // Q fragments (16 rows per wave), pre-scaled by SC
    bf16x8_t qf[2];
    #pragma unroll
    for (int k0 = 0; k0 < 2; k0++) {
        int row = qt0 + w * 16 + rl;
        bf16x8_t qr = *(const bf16x8_t*)(Q + base + (size_t)row * DMODEL + k0 * 32 + rh * 8);
        #pragma unroll
        for (int j = 0; j < 8; j++)
            qf[k0][j] = (short)f2bf(bf2f((u16)qr[j]) * SC);
    }

    f32x4 oacc[4];
    float mrun = -INFINITY, lrun = 0.f;      // per-lane: q-row = rl
    #pragma unroll
    for (int nd = 0; nd < 4; nd++) oacc[nd] = (f32x4){0.f, 0.f, 0.f, 0.f};

    // --- prologue: stage K(0) -> Kls[0], V(0) -> Vt[0] ---
    #pragma unroll
    for (int c = 0; c < 2; c++) {
        int kr = w * 16 + c * 8 + krl8;
        int sseg = ks ^ ((kr ^ (kr >> 3)) & 7);
        gload_lds16(Kp + base + (size_t)kr * DMODEL + sseg * 8,
                    &Kls[0][(w * 16 + c * 8) * 64]);
    }
    {
        const u16* vg = Vp + base + (size_t)(2 * rpair) * DMODEL + dseg * 8;
        bf16x8_t v0 = *(const bf16x8_t*)vg;
        bf16x8_t v1 = *(const bf16x8_t*)(vg + DMODEL);
        #pragma unroll
        for (int j = 0; j < 8; j++) {
            int d = dseg * 8 + j;
            u32 pk = (u32)(u16)v0[j] | ((u32)(u16)v1[j] << 16);
            *(u32*)((char*)&Vt[0][0] + ((d * 128 + rpair * 4) ^ swz(d))) = pk;
        }
    }
    __syncthreads();

    for (int t = 0; t < nt; t++) {
        const int cur = t & 1;
        const bool more = (t + 1 < nt);
        bf16x8_t vv0, vv1;

        // issue K(t+1) -> Kls[cur^1] (arrives at end-of-tile barrier)
        // and V(t+1) reg loads (written to LDS after PV)
        if (more) {
            #pragma unroll
            for (int c = 0; c < 2; c++) {
                int kr = w * 16 + c * 8 + krl8;
                int sseg = ks ^ ((kr ^ (kr >> 3)) & 7);
                gload_lds16(Kp + base + (size_t)((t + 1) * 64 + kr) * DMODEL + sseg * 8,
                            &Kls[cur ^ 1][(w * 16 + c * 8) * 64]);
            }
            const u16* vg = Vp + base + (size_t)((t + 1) * 64 + 2 * rpair) * DMODEL + dseg * 8;
            vv0 = *(const bf16x8_t*)vg;
            vv1 = *(const bf16x8_t*)(vg + DMODEL);
        }

        // --- S^T = K Q^T : sa[ni][j] holds q = rl, kv = ni*16+rh*4+j ---
        f32x4 sa[4];
        #pragma unroll
        for (int ni = 0; ni < 4; ni++) sa[ni] = (f32x4){0.f, 0.f, 0.f, 0.f};
        __builtin_amdgcn_s_setprio(1);
        #pragma unroll
        for (int k0 = 0; k0 < 2; k0++) {
            bf16x8_t kf[4];
            #pragma unroll
            for (int ni = 0; ni < 4; ni++) {
                int row = ni * 16 + rl;
                kf[ni] = *(const bf16x8_t*)((const char*)&Kls[cur][0] +
                          (((row * 64 + k0 * 32 + rh * 8) * 2) ^ swz(row)));
            }
            #pragma unroll
            for (int ni = 0; ni < 4; ni++)
                sa[ni] = __builtin_amdgcn_mfma_f32_16x16x32_bf16(
                    kf[ni], qf[k0], sa[ni], 0, 0, 0);
        }
        __builtin_amdgcn_s_setprio(0);

        // --- causal mask (diag tile only): kv_local > q_local ---
        if (t + 1 == nt) {
            const int ql = w * 16 + rl;
            #pragma unroll
            for (int ni = 0; ni < 4; ni++)
                #pragma unroll
                for (int j = 0; j < 4; j++)
                    if (ni * 16 + rh * 4 + j > ql) sa[ni][j] = -INFINITY;
        }

        // --- in-lane row max (tree) + 2-step cross-rh reduce ---
        float m0, m1, m2, m3, mx;
        m0 = fmaxf(fmaxf(sa[0][0], sa[0][1]), fmaxf(sa[0][2], sa[0][3]));
        m1 = fmaxf(fmaxf(sa[1][0], sa[1][1]), fmaxf(sa[1][2], sa[1][3]));
        m2 = fmaxf(fmaxf(sa[2][0], sa[2][1]), fmaxf(sa[2][2], sa[2][3]));
        m3 = fmaxf(fmaxf(sa[3][0], sa[3][1]), fmaxf(sa[3][2], sa[3][3]));
        mx = fmaxf(fmaxf(m0, m1), fmaxf(m2, m3));
        mx = fmaxf(mx, __shfl_xor(mx, 16, 64));
        mx = fmaxf(mx, __shfl_xor(mx, 32, 64));

        // --- T13 defer-max: rescale only when max grew > 8 (log2) ---
        if (__any(mx - mrun > 8.f)) {
            const float mn = fmaxf(mrun, mx);
            const float alpha = exp2f(mrun - mn);   // for q-row rl
            mrun = mn;
            lrun *= alpha;
            #pragma unroll
            for (int j = 0; j < 4; j++) {
                // oacc rows are q = rh*4+j -> fetch that row's alpha
                float aj = __shfl(alpha, (l & 48) | (rh * 4 + j), 64);
                #pragma unroll
                for (int nd = 0; nd < 4; nd++) oacc[nd][j] *= aj;
            }
        }

        // --- exp + in-lane sum + 2-step cross-rh reduce ---
        float s0 = 0.f, s1 = 0.f;
        #pragma unroll
        for (int ni = 0; ni < 4; ni++) {
            #pragma unroll
            for (int j = 0; j < 4; j++) {
                float p = exp2f(sa[ni][j] - mrun);
                sa[ni][j] = p;
                if (ni < 2) s0 += p; else s1 += p;
            }
        }
        float ss = s0 + s1;
        ss += __shfl_xor(ss, 16, 64);
        ss += __shfl_xor(ss, 32, 64);
        lrun += ss;

        // P (bf16) -> per-wave LDS [q=rl][kv], cvt_pk + packed b64 writes
        #pragma unroll
        for (int ni = 0; ni < 4; ni++) {
            u32x2 pk;
            pk.x = cvt_pk_bf16(sa[ni][0], sa[ni][1]);
            pk.y = cvt_pk_bf16(sa[ni][2], sa[ni][3]);
            *(u32x2*)((char*)&Pls[w][0] +
                      (((rl * 64 + ni * 16 + rh * 4) * 2) ^ swz(rl))) = pk;
        }

        // --- O += P V ---
        __builtin_amdgcn_s_setprio(1);
        #pragma unroll
        for (int k0 = 0; k0 < 2; k0++) {
            bf16x8_t pf = *(const bf16x8_t*)((const char*)&Pls[w][0] +
                           (((rl * 64 + k0 * 32 + rh * 8) * 2) ^ swz(rl)));
            bf16x8_t vf[4];
            #pragma unroll
            for (int nd = 0; nd < 4; nd++) {
                int row = nd * 16 + rl;
                vf[nd] = *(const bf16x8_t*)((const char*)&Vt[cur][0] +
                          (((row * 64 + k0 * 32 + rh * 8) * 2) ^ swz(row)));
            }
            #pragma unroll
            for (int nd = 0; nd < 4; nd++)
                oacc[nd] = __builtin_amdgcn_mfma_f32_16x16x32_bf16(
                    pf, vf[nd], oacc[nd], 0, 0, 0);
        }
        __builtin_amdgcn_s_setprio(0);

        // stage V(t+1) into the other buffer (its last reader was tile t-1,
        // protected by the previous barrier)
        if (more) {
            #pragma unroll
            for (int j = 0; j < 8; j++) {
                int d = dseg * 8 + j;
                u32 pk = (u32)(u16)vv0[j] | ((u32)(u16)vv1[j] << 16);
                *(u32*)((char*)&Vt[cur ^ 1][0] + ((d * 128 + rpair * 4) ^ swz(d))) = pk;
            }
        }
        __syncthreads();
    }

    // epilogue: O / l -> global (bf16); l for row q=rh*4+j via shfl
    float lq[4];
    #pragma unroll
    for (int j = 0; j < 4; j++)
        lq[j] = __shfl(lrun, (l & 48) | (rh * 4 + j), 64);
    #pragma unroll
    for (int nd = 0; nd < 4; nd++)
        #pragma unroll
        for (int j = 0; j < 4; j++) {
            int row = qt0 + w * 16 + rh * 4 + j;
            O[base + (size_t)row * DMODEL + nd * 16 + rl] =
                f2bf(oacc[nd][j] / lq[j]);
        }
}

// ---------------------------------------------------------------------------
extern "C" void kernel_launch(void* const* d_in, const int* in_sizes, int n_in,
                              void* d_out, int out_size, void* d_ws, size_t ws_size,
                              hipStream_t stream)
{
    const float* x  = (const float*)d_in[0];
    const float* wq = (const float*)d_in[1];
    const float* wk = (const float*)d_in[2];
    const float* wv = (const float*)d_in[3];
    const float* wo = (const float*)d_in[4];
    float* out = (float*)d_out;

    const size_t NX = (size_t)4096 * 1024;   // B*S*D
    const size_t NW = (size_t)1024 * 1024;

    u16* xb  = (u16*)d_ws;
    u16* wqb = xb  + NX;
    u16* wkb = wqb + NW;
    u16* wvb = wkb + NW;
    u16* wob = wvb + NW;
    u16* q   = wob + NW;
    u16* k   = q   + NX;
    u16* v   = k   + NX;
    u16* at  = v   + NX;

    // 8 elems/thread: x needs 4M/2048 = 2048 blocks; weights exit early
    cvt5<<<dim3(2048, 5), 256, 0, stream>>>(x, wq, wk, wv, wo,
                                            xb, wqb, wkb, wvb, wob,
                                            (int)NX, (int)NW, (int)NW, (int)NW, (int)NW);

    // Q/K/V projections: (4096x1024) @ (1024x1024)^T, fused over grid.z
    gemm_bt<1, 128><<<dim3(32, 8, 3), 256, 0, stream>>>(xb, wqb, wkb, wvb,
                                                        q, k, v, 4096, 1024, 1024);

    attn_fwd<<<dim3(32, 32), 256, 0, stream>>>(q, k, v, at);

    // output projection -> fp32 (BN=64 tile)
    gemm_bt<0, 64><<<dim3(32, 16, 1), 256, 0, stream>>>(at, wob, wob, wob,
                                                        out, out, out, 4096, 1024, 1024);
}